// Round 4
// baseline (925.585 us; speedup 1.0000x reference)
//
#include <hip/hip_runtime.h>

// B=4, T=2048, D_MODEL=2048, H=16, KV=8, HD=128, G=2. f32 storage in/out,
// bf16 MFMA internals, fp32 accum. Compare threshold is bf16-lenient.

typedef unsigned short u16;
typedef unsigned int u32;
typedef __attribute__((ext_vector_type(8))) short bf16x8;
typedef __attribute__((ext_vector_type(4))) float f32x4;

__device__ __forceinline__ float bf2f(u16 v) {
    union { u32 u; float f; } x; x.u = ((u32)v) << 16; return x.f;
}
__device__ __forceinline__ u16 f2bf(float f) {
    union { float f; u32 u; } x; x.f = f;
    u32 u = x.u;
    return (u16)((u + 0x7FFFu + ((u >> 16) & 1u)) >> 16);  // RNE
}
// truncating pack of two f32 -> two bf16 (hot loop only; p >= 0)
__device__ __forceinline__ u32 packtrunc(float a, float b) {
    union { float f; u32 u; } x, y; x.f = a; y.f = b;
    return (x.u >> 16) | (y.u & 0xffff0000u);
}
__device__ __forceinline__ f32x4 mfma_bf16(bf16x8 a, bf16x8 b, f32x4 c) {
    return __builtin_amdgcn_mfma_f32_16x16x32_bf16(a, b, c, 0, 0, 0);
}
// async global->LDS, 16B per lane; LDS dest = wave-uniform base + lane*16
__device__ __forceinline__ void gl_lds16(const u16* g, u16* l) {
    __builtin_amdgcn_global_load_lds((const __attribute__((address_space(1))) void*)g,
                                     (__attribute__((address_space(3))) void*)l, 16, 0, 0);
}

// ---------------------------------------------------------------------------
// Transpose + cast f32 -> bf16: in[R][C] f32 -> out[C][R] bf16.
// ---------------------------------------------------------------------------
__global__ __launch_bounds__(256)
void transpose_f2b(const float* __restrict__ in, u16* __restrict__ out, int R, int C) {
    __shared__ float tile[32][33];
    const int tx = threadIdx.x & 31, ty = threadIdx.x >> 5;
    const long c0 = (long)blockIdx.x * 32, r0 = (long)blockIdx.y * 32;
#pragma unroll
    for (int i = 0; i < 4; i++)
        tile[ty + i * 8][tx] = in[(r0 + ty + i * 8) * C + c0 + tx];
    __syncthreads();
#pragma unroll
    for (int i = 0; i < 4; i++)
        out[(c0 + ty + i * 8) * R + r0 + tx] = f2bf(tile[tx][ty + i * 8]);
}

// ---------------------------------------------------------------------------
// Straight cast f32 -> bf16, 8 elem/thread.
// ---------------------------------------------------------------------------
__global__ __launch_bounds__(256)
void cast_f2b(const float* __restrict__ in, u16* __restrict__ out) {
    const long i = ((long)blockIdx.x * 256 + threadIdx.x) * 8;
    float4 a = *(const float4*)(in + i);
    float4 b = *(const float4*)(in + i + 4);
    bf16x8 v;
    v[0] = (short)f2bf(a.x); v[1] = (short)f2bf(a.y);
    v[2] = (short)f2bf(a.z); v[3] = (short)f2bf(a.w);
    v[4] = (short)f2bf(b.x); v[5] = (short)f2bf(b.y);
    v[6] = (short)f2bf(b.z); v[7] = (short)f2bf(b.w);
    *(bf16x8*)(out + i) = v;
}

// ---------------------------------------------------------------------------
// bf16 transpose of the V slice of qkv: qkv[token][3072 + d'] -> Vt[b][d'][t]
// ---------------------------------------------------------------------------
__global__ __launch_bounds__(256)
void transpose_v(const u16* __restrict__ qkv, u16* __restrict__ Vt) {
    __shared__ u16 tile[32][33];
    const int tx = threadIdx.x & 31, ty = threadIdx.x >> 5;
    const int d0 = blockIdx.x * 32;
    const int tok0 = blockIdx.y * 32;
#pragma unroll
    for (int i = 0; i < 4; i++)
        tile[ty + i * 8][tx] = qkv[(long)(tok0 + ty + i * 8) * 4096 + 3072 + d0 + tx];
    __syncthreads();
    const int b = tok0 >> 11;
    const long orow = (long)b * 1024 + d0;
    const int t0 = tok0 & 2047;
#pragma unroll
    for (int i = 0; i < 4; i++)
        Vt[(orow + ty + i * 8) * 2048 + t0 + tx] = tile[tx][ty + i * 8];
}

// ---------------------------------------------------------------------------
// GEMM (m97 structure): C[M][N] = A[M][K] @ Bt[N][K]^T, bf16, fp32 accum.
// 128x128 tile, BK=32, flat LDS, global_load_lds width-16 staging.
// ---------------------------------------------------------------------------
template <bool F32OUT>
__global__ __launch_bounds__(256)
void gemm_bt_bf16(const u16* __restrict__ A, const u16* __restrict__ Bt,
                  void* __restrict__ Cp, int M, int N, int K) {
    __shared__ __align__(16) u16 As[128 * 32];
    __shared__ __align__(16) u16 Bs[128 * 32];
    const int tid = threadIdx.x, wid = tid >> 6, lane = tid & 63;
    const int q4 = lane >> 4, n16 = lane & 15;
    const int wr = (wid >> 1) * 64, wc = (wid & 1) * 64;
    const long rowT = (long)blockIdx.y * 128, colT = (long)blockIdx.x * 128;

    const int srow = wid * 32 + (lane >> 2);
    const int scol = (lane & 3) * 8;
    const u16* Ag0 = A + (rowT + srow) * K + scol;
    const u16* Ag1 = Ag0 + (long)16 * K;
    const u16* Bg0 = Bt + (colT + srow) * K + scol;
    const u16* Bg1 = Bg0 + (long)16 * K;
    u16* la0 = As + wid * 1024 + lane * 8;
    u16* la1 = la0 + 512;
    u16* lb0 = Bs + wid * 1024 + lane * 8;
    u16* lb1 = lb0 + 512;

    f32x4 acc[4][4];
#pragma unroll
    for (int i = 0; i < 4; i++)
#pragma unroll
        for (int j = 0; j < 4; j++) acc[i][j] = (f32x4){0.f, 0.f, 0.f, 0.f};

    for (int k0 = 0; k0 < K; k0 += 32) {
        gl_lds16(Ag0 + k0, la0);
        gl_lds16(Ag1 + k0, la1);
        gl_lds16(Bg0 + k0, lb0);
        gl_lds16(Bg1 + k0, lb1);
        __syncthreads();
        bf16x8 af[4], bfr[4];
#pragma unroll
        for (int mb = 0; mb < 4; mb++) af[mb]  = *(const bf16x8*)&As[(wr + mb * 16 + n16) * 32 + q4 * 8];
#pragma unroll
        for (int nb = 0; nb < 4; nb++) bfr[nb] = *(const bf16x8*)&Bs[(wc + nb * 16 + n16) * 32 + q4 * 8];
#pragma unroll
        for (int mb = 0; mb < 4; mb++)
#pragma unroll
            for (int nb = 0; nb < 4; nb++)
                acc[mb][nb] = mfma_bf16(af[mb], bfr[nb], acc[mb][nb]);
        __syncthreads();
    }

#pragma unroll
    for (int mb = 0; mb < 4; mb++)
#pragma unroll
        for (int nb = 0; nb < 4; nb++)
#pragma unroll
            for (int r = 0; r < 4; r++) {
                long row = rowT + wr + mb * 16 + q4 * 4 + r;
                long col = colT + wc + nb * 16 + n16;
                if (F32OUT) ((float*)Cp)[row * N + col] = acc[mb][nb][r];
                else        ((u16*)Cp)[row * N + col]   = f2bf(acc[mb][nb][r]);
            }
}

// ---------------------------------------------------------------------------
// RMSNorm + interleaved RoPE in-place on bf16 qkv [8192][4096].
// q-heads scaled by (1/sqrt(128))*log2(e): folds softmax scale + exp2 domain.
// ---------------------------------------------------------------------------
__global__ __launch_bounds__(256)
void rmsnorm_rope(u16* __restrict__ qkv, const float* __restrict__ cosT,
                  const float* __restrict__ sinT, const float* __restrict__ qg,
                  const float* __restrict__ kg) {
    const int w = blockIdx.x * 4 + (threadIdx.x >> 6);
    const int lane = threadIdx.x & 63;
    const int token = w / 24;
    const int hv = w - token * 24;
    const long base = (long)token * 4096 + (hv < 16 ? hv * 128 : 2048 + (hv - 16) * 128);
    const float* g = (hv < 16) ? qg : kg;
    const int t = token & 2047;

    u32 pair = *(const u32*)(qkv + base + 2 * lane);
    float a0 = bf2f((u16)(pair & 0xffffu));
    float a1 = bf2f((u16)(pair >> 16));
    float ss = a0 * a0 + a1 * a1;
#pragma unroll
    for (int off = 32; off > 0; off >>= 1) ss += __shfl_xor(ss, off);
    float rs = rsqrtf(ss * (1.0f / 128.0f) + 1e-6f);
    float h0 = a0 * rs * g[2 * lane];
    float h1 = a1 * rs * g[2 * lane + 1];
    float2 cp = *(const float2*)(cosT + (long)t * 128 + 2 * lane);
    float2 sp = *(const float2*)(sinT + (long)t * 128 + 2 * lane);
    float o0 = h0 * cp.x - h1 * sp.x;
    float o1 = h1 * cp.y + h0 * sp.y;
    if (hv < 16) {
        const float QS = 0.08838834764831845f * 1.4426950408889634f;
        o0 *= QS; o1 *= QS;
    }
    *(u32*)(qkv + base + 2 * lane) = ((u32)f2bf(o0)) | (((u32)f2bf(o1)) << 16);
}

// ---------------------------------------------------------------------------
// Flash attention, transposed-scores, barrier-free, FIXED-SHIFT softmax.
// RMSNorm guarantees |score*log2e| <= 128/sqrt(128)*log2e = 16.33, so
// p = exp2(s' - 18) is exact softmax up to a uniform scale that cancels in
// p/l. No running max, no alpha rescale, no shuffles in the K loop -> the
// only cross-tile dependency is the O/l accumulate at chain end.
// Grid (16, 64): x = 128-row Q tile, y = b*16+h. Wave owns 32 Q-rows.
// ---------------------------------------------------------------------------
__global__ __launch_bounds__(256)
void flash_attn(const u16* __restrict__ qkv, const u16* __restrict__ Vt,
                u16* __restrict__ attn) {
    __shared__ __align__(16) u16 Ps[4][32][72];   // wave-private, pad 64->72
    const int tid = threadIdx.x, wid = tid >> 6, lane = tid & 63;
    const int q4 = lane >> 4, n16 = lane & 15;
    const int b = blockIdx.y >> 4, h = blockIdx.y & 15;
    const int kvh = h >> 1;
    const long rowbase = (long)b * 2048;
    const long qbase = rowbase + (long)blockIdx.x * 128 + wid * 32;

    // Q B-frags (resident)
    bf16x8 qf[2][4];
#pragma unroll
    for (int qb = 0; qb < 2; qb++) {
        const u16* p = qkv + (qbase + qb * 16 + n16) * 4096 + h * 128;
#pragma unroll
        for (int c = 0; c < 4; c++) qf[qb][c] = *(const bf16x8*)(p + c * 32 + q4 * 8);
    }

    f32x4 o[2][8];
#pragma unroll
    for (int i = 0; i < 2; i++)
#pragma unroll
        for (int j = 0; j < 8; j++) o[i][j] = (f32x4){0.f, 0.f, 0.f, 0.f};
    float l_i[2] = {0.f, 0.f};            // per-lane partial (own quad's keys)
    const float SHIFT = 18.0f;            // >= 16.33 hard bound, margin for bf16

    const u16* Kbase = qkv + rowbase * 4096 + 2048 + kvh * 128;     // + t*4096 + d
    const u16* Vbase = Vt + ((long)(b * 8 + kvh) * 128) * 2048;     // + d*2048 + t

    for (int kt = 0; kt < 2048; kt += 64) {
        // ---- S^T = K Q^T : A-frag = K rows (direct global), B-frag = qf ----
        f32x4 s[2][4];
#pragma unroll
        for (int qb = 0; qb < 2; qb++)
#pragma unroll
            for (int kb = 0; kb < 4; kb++) s[qb][kb] = (f32x4){0.f, 0.f, 0.f, 0.f};
#pragma unroll
        for (int c = 0; c < 4; c++) {
            bf16x8 kf[4];
#pragma unroll
            for (int kb = 0; kb < 4; kb++)
                kf[kb] = *(const bf16x8*)(Kbase + (long)(kt + kb * 16 + n16) * 4096 + c * 32 + q4 * 8);
#pragma unroll
            for (int qb = 0; qb < 2; qb++)
#pragma unroll
                for (int kb = 0; kb < 4; kb++)
                    s[qb][kb] = mfma_bf16(kf[kb], qf[qb][c], s[qb][kb]);
        }

        // ---- fixed-shift exp2; accumulate l per lane; pack P to bf16 ----
#pragma unroll
        for (int qb = 0; qb < 2; qb++) {
            float sum = 0.f;
#pragma unroll
            for (int kb = 0; kb < 4; kb++) {
                float p0 = exp2f(s[qb][kb][0] - SHIFT);
                float p1 = exp2f(s[qb][kb][1] - SHIFT);
                float p2 = exp2f(s[qb][kb][2] - SHIFT);
                float p3 = exp2f(s[qb][kb][3] - SHIFT);
                sum += (p0 + p1) + (p2 + p3);
                *(uint2*)&Ps[wid][qb * 16 + n16][kb * 16 + q4 * 4] =
                    make_uint2(packtrunc(p0, p1), packtrunc(p2, p3));
            }
            l_i[qb] += sum;
        }

        // ---- PV: A = P-frag (wave-private LDS), B = V^T-frag (direct global) ----
#pragma unroll
        for (int kc = 0; kc < 2; kc++) {
            bf16x8 vf[8];
#pragma unroll
            for (int nbh = 0; nbh < 8; nbh++)
                vf[nbh] = *(const bf16x8*)(Vbase + (long)(nbh * 16 + n16) * 2048 + kt + kc * 32 + q4 * 8);
#pragma unroll
            for (int qb = 0; qb < 2; qb++) {
                bf16x8 pf = *(const bf16x8*)&Ps[wid][qb * 16 + n16][kc * 32 + q4 * 8];
#pragma unroll
                for (int nbh = 0; nbh < 8; nbh++)
                    o[qb][nbh] = mfma_bf16(pf, vf[nbh], o[qb][nbh]);
            }
        }
    }

    // ---- reduce l across the 4 quads (keys were split across quads) ----
#pragma unroll
    for (int qb = 0; qb < 2; qb++) {
        l_i[qb] += __shfl_xor(l_i[qb], 16);
        l_i[qb] += __shfl_xor(l_i[qb], 32);
    }

    // ---- epilogue: O /= l, write bf16 attn[8192][2048] ----
#pragma unroll
    for (int qb = 0; qb < 2; qb++) {
        float linv = 1.0f / l_i[qb];
        float l4[4];
#pragma unroll
        for (int r = 0; r < 4; r++)
            l4[r] = __shfl(linv, (lane & 48) | (q4 * 4 + r));
#pragma unroll
        for (int r = 0; r < 4; r++) {
            u16* op = attn + (qbase + qb * 16 + q4 * 4 + r) * 2048 + h * 128 + n16;
#pragma unroll
            for (int nbh = 0; nbh < 8; nbh++)
                op[nbh * 16] = f2bf(o[qb][nbh][r] * l4[r]);
        }
    }
}

// ---------------------------------------------------------------------------
// ws layout (bytes), total 125.8 MB:
//   Bt_qkv / Vt  @ 0          16,777,216   (Vt overwrites Bt_qkv after gemm_qkv)
//   Bt_o         @ 16777216    8,388,608
//   xb / attn    @ 25165824   33,554,432   (attn overwrites xb after gemm_qkv)
//   qkv          @ 58720256   67,108,864
// ---------------------------------------------------------------------------
extern "C" void kernel_launch(void* const* d_in, const int* in_sizes, int n_in,
                              void* d_out, int out_size, void* d_ws, size_t ws_size,
                              hipStream_t stream) {
    const float* x    = (const float*)d_in[0];
    const float* cosT = (const float*)d_in[1];
    const float* sinT = (const float*)d_in[2];
    const float* Wq   = (const float*)d_in[3];
    const float* Wk   = (const float*)d_in[4];
    const float* Wv   = (const float*)d_in[5];
    const float* Wo   = (const float*)d_in[6];
    const float* qg   = (const float*)d_in[7];
    const float* kg   = (const float*)d_in[8];
    float* out = (float*)d_out;

    char* ws = (char*)d_ws;
    u16* Bt_qkv = (u16*)(ws);
    u16* Vt     = (u16*)(ws);              // reuses Bt_qkv after gemm_qkv
    u16* Bt_o   = (u16*)(ws + 16777216);
    u16* xb     = (u16*)(ws + 25165824);
    u16* attn   = (u16*)(ws + 25165824);   // reuses xb after gemm_qkv
    u16* qkv    = (u16*)(ws + 58720256);

    transpose_f2b<<<dim3(64, 64), 256, 0, stream>>>(Wq, Bt_qkv, 2048, 2048);
    transpose_f2b<<<dim3(32, 64), 256, 0, stream>>>(Wk, Bt_qkv + (size_t)2048 * 2048, 2048, 1024);
    transpose_f2b<<<dim3(32, 64), 256, 0, stream>>>(Wv, Bt_qkv + (size_t)3072 * 2048, 2048, 1024);
    transpose_f2b<<<dim3(64, 64), 256, 0, stream>>>(Wo, Bt_o, 2048, 2048);
    cast_f2b<<<dim3(8192), 256, 0, stream>>>(x, xb);

    gemm_bt_bf16<false><<<dim3(32, 64), 256, 0, stream>>>(xb, Bt_qkv, qkv, 8192, 4096, 2048);

    transpose_v<<<dim3(32, 256), 256, 0, stream>>>(qkv, Vt);
    rmsnorm_rope<<<dim3(49152), 256, 0, stream>>>(qkv, cosT, sinT, qg, kg);

    flash_attn<<<dim3(16, 64), 256, 0, stream>>>(qkv, Vt, attn);

    gemm_bt_bf16<true><<<dim3(16, 64), 256, 0, stream>>>(attn, Bt_o, out, 8192, 2048, 2048);
}

// Round 5
// 748.190 us; speedup vs baseline: 1.2371x; 1.2371x over previous
//
#include <hip/hip_runtime.h>

// B=4, T=2048, D_MODEL=2048, H=16, KV=8, HD=128, G=2. f32 storage in/out,
// bf16 MFMA internals, fp32 accum. Compare threshold is bf16-lenient.

typedef unsigned short u16;
typedef unsigned int u32;
typedef __attribute__((ext_vector_type(8))) short bf16x8;
typedef __attribute__((ext_vector_type(4))) float f32x4;

__device__ __forceinline__ float bf2f(u16 v) {
    union { u32 u; float f; } x; x.u = ((u32)v) << 16; return x.f;
}
__device__ __forceinline__ u16 f2bf(float f) {
    union { float f; u32 u; } x; x.f = f;
    u32 u = x.u;
    return (u16)((u + 0x7FFFu + ((u >> 16) & 1u)) >> 16);  // RNE
}
// truncating pack of two f32 -> two bf16 (p >= 0, hot loop only)
__device__ __forceinline__ u32 packtrunc(float a, float b) {
    union { float f; u32 u; } x, y; x.f = a; y.f = b;
    return (x.u >> 16) | (y.u & 0xffff0000u);
}
__device__ __forceinline__ f32x4 mfma_bf16(bf16x8 a, bf16x8 b, f32x4 c) {
    return __builtin_amdgcn_mfma_f32_16x16x32_bf16(a, b, c, 0, 0, 0);
}
// async global->LDS, 16B/lane; LDS dest = wave-uniform base + lane*16
__device__ __forceinline__ void gl_lds16(const u16* g, u16* l) {
    __builtin_amdgcn_global_load_lds((const __attribute__((address_space(1))) void*)g,
                                     (__attribute__((address_space(3))) void*)l, 16, 0, 0);
}

// ---------------------------------------------------------------------------
// Transpose + cast f32 -> bf16: in[R][C] f32 -> out[C][R] bf16.
// ---------------------------------------------------------------------------
__global__ __launch_bounds__(256)
void transpose_f2b(const float* __restrict__ in, u16* __restrict__ out, int R, int C) {
    __shared__ float tile[32][33];
    const int tx = threadIdx.x & 31, ty = threadIdx.x >> 5;
    const long c0 = (long)blockIdx.x * 32, r0 = (long)blockIdx.y * 32;
#pragma unroll
    for (int i = 0; i < 4; i++)
        tile[ty + i * 8][tx] = in[(r0 + ty + i * 8) * C + c0 + tx];
    __syncthreads();
#pragma unroll
    for (int i = 0; i < 4; i++)
        out[(c0 + ty + i * 8) * R + r0 + tx] = f2bf(tile[tx][ty + i * 8]);
}

// ---------------------------------------------------------------------------
// Straight cast f32 -> bf16, 8 elem/thread.
// ---------------------------------------------------------------------------
__global__ __launch_bounds__(256)
void cast_f2b(const float* __restrict__ in, u16* __restrict__ out) {
    const long i = ((long)blockIdx.x * 256 + threadIdx.x) * 8;
    float4 a = *(const float4*)(in + i);
    float4 b = *(const float4*)(in + i + 4);
    bf16x8 v;
    v[0] = (short)f2bf(a.x); v[1] = (short)f2bf(a.y);
    v[2] = (short)f2bf(a.z); v[3] = (short)f2bf(a.w);
    v[4] = (short)f2bf(b.x); v[5] = (short)f2bf(b.y);
    v[6] = (short)f2bf(b.z); v[7] = (short)f2bf(b.w);
    *(bf16x8*)(out + i) = v;
}

// ---------------------------------------------------------------------------
// bf16 transpose of the V slice of qkv: qkv[token][3072 + d'] -> Vt[b][d'][t]
// ---------------------------------------------------------------------------
__global__ __launch_bounds__(256)
void transpose_v(const u16* __restrict__ qkv, u16* __restrict__ Vt) {
    __shared__ u16 tile[32][33];
    const int tx = threadIdx.x & 31, ty = threadIdx.x >> 5;
    const int d0 = blockIdx.x * 32;
    const int tok0 = blockIdx.y * 32;
#pragma unroll
    for (int i = 0; i < 4; i++)
        tile[ty + i * 8][tx] = qkv[(long)(tok0 + ty + i * 8) * 4096 + 3072 + d0 + tx];
    __syncthreads();
    const int b = tok0 >> 11;
    const long orow = (long)b * 1024 + d0;
    const int t0 = tok0 & 2047;
#pragma unroll
    for (int i = 0; i < 4; i++)
        Vt[(orow + ty + i * 8) * 2048 + t0 + tx] = tile[tx][ty + i * 8];
}

// ---------------------------------------------------------------------------
// GEMM (m97 structure): C[M][N] = A[M][K] @ Bt[N][K]^T, bf16, fp32 accum.
// ---------------------------------------------------------------------------
template <bool F32OUT>
__global__ __launch_bounds__(256)
void gemm_bt_bf16(const u16* __restrict__ A, const u16* __restrict__ Bt,
                  void* __restrict__ Cp, int M, int N, int K) {
    __shared__ __align__(16) u16 As[128 * 32];
    __shared__ __align__(16) u16 Bs[128 * 32];
    const int tid = threadIdx.x, wid = tid >> 6, lane = tid & 63;
    const int q4 = lane >> 4, n16 = lane & 15;
    const int wr = (wid >> 1) * 64, wc = (wid & 1) * 64;
    const long rowT = (long)blockIdx.y * 128, colT = (long)blockIdx.x * 128;

    const int srow = wid * 32 + (lane >> 2);
    const int scol = (lane & 3) * 8;
    const u16* Ag0 = A + (rowT + srow) * K + scol;
    const u16* Ag1 = Ag0 + (long)16 * K;
    const u16* Bg0 = Bt + (colT + srow) * K + scol;
    const u16* Bg1 = Bg0 + (long)16 * K;
    u16* la0 = As + wid * 1024 + lane * 8;
    u16* la1 = la0 + 512;
    u16* lb0 = Bs + wid * 1024 + lane * 8;
    u16* lb1 = lb0 + 512;

    f32x4 acc[4][4];
#pragma unroll
    for (int i = 0; i < 4; i++)
#pragma unroll
        for (int j = 0; j < 4; j++) acc[i][j] = (f32x4){0.f, 0.f, 0.f, 0.f};

    for (int k0 = 0; k0 < K; k0 += 32) {
        gl_lds16(Ag0 + k0, la0);
        gl_lds16(Ag1 + k0, la1);
        gl_lds16(Bg0 + k0, lb0);
        gl_lds16(Bg1 + k0, lb1);
        __syncthreads();
        bf16x8 af[4], bfr[4];
#pragma unroll
        for (int mb = 0; mb < 4; mb++) af[mb]  = *(const bf16x8*)&As[(wr + mb * 16 + n16) * 32 + q4 * 8];
#pragma unroll
        for (int nb = 0; nb < 4; nb++) bfr[nb] = *(const bf16x8*)&Bs[(wc + nb * 16 + n16) * 32 + q4 * 8];
#pragma unroll
        for (int mb = 0; mb < 4; mb++)
#pragma unroll
            for (int nb = 0; nb < 4; nb++)
                acc[mb][nb] = mfma_bf16(af[mb], bfr[nb], acc[mb][nb]);
        __syncthreads();
    }

#pragma unroll
    for (int mb = 0; mb < 4; mb++)
#pragma unroll
        for (int nb = 0; nb < 4; nb++)
#pragma unroll
            for (int r = 0; r < 4; r++) {
                long row = rowT + wr + mb * 16 + q4 * 4 + r;
                long col = colT + wc + nb * 16 + n16;
                if (F32OUT) ((float*)Cp)[row * N + col] = acc[mb][nb][r];
                else        ((u16*)Cp)[row * N + col]   = f2bf(acc[mb][nb][r]);
            }
}

// ---------------------------------------------------------------------------
// RMSNorm + interleaved RoPE in-place on bf16 qkv [8192][4096].
// q-heads scaled by (1/sqrt(128))*log2(e): folds softmax scale + exp2 domain.
// ---------------------------------------------------------------------------
__global__ __launch_bounds__(256)
void rmsnorm_rope(u16* __restrict__ qkv, const float* __restrict__ cosT,
                  const float* __restrict__ sinT, const float* __restrict__ qg,
                  const float* __restrict__ kg) {
    const int w = blockIdx.x * 4 + (threadIdx.x >> 6);
    const int lane = threadIdx.x & 63;
    const int token = w / 24;
    const int hv = w - token * 24;
    const long base = (long)token * 4096 + (hv < 16 ? hv * 128 : 2048 + (hv - 16) * 128);
    const float* g = (hv < 16) ? qg : kg;
    const int t = token & 2047;

    u32 pair = *(const u32*)(qkv + base + 2 * lane);
    float a0 = bf2f((u16)(pair & 0xffffu));
    float a1 = bf2f((u16)(pair >> 16));
    float ss = a0 * a0 + a1 * a1;
#pragma unroll
    for (int off = 32; off > 0; off >>= 1) ss += __shfl_xor(ss, off);
    float rs = rsqrtf(ss * (1.0f / 128.0f) + 1e-6f);
    float h0 = a0 * rs * g[2 * lane];
    float h1 = a1 * rs * g[2 * lane + 1];
    float2 cp = *(const float2*)(cosT + (long)t * 128 + 2 * lane);
    float2 sp = *(const float2*)(sinT + (long)t * 128 + 2 * lane);
    float o0 = h0 * cp.x - h1 * sp.x;
    float o1 = h1 * cp.y + h0 * sp.y;
    if (hv < 16) {
        const float QS = 0.08838834764831845f * 1.4426950408889634f;
        o0 *= QS; o1 *= QS;
    }
    *(u32*)(qkv + base + 2 * lane) = ((u32)f2bf(o0)) | (((u32)f2bf(o1)) << 16);
}

// ---------------------------------------------------------------------------
// Flash attention v3: LDS-staged K/V (coalesced global_load_lds + XOR chunk
// swizzle), transposed scores, fixed-shift softmax.
// Grid (16, 64): x = 128-row Q tile, y = b*16+h. 4 waves, wave owns 32 rows.
// K-tile = 64 keys. Ks[64][128] (swizzled), Vs[128][64] (swizzled, V^T),
// Ps wave-private. Swizzle: 16B chunk j of row r lives at slot j^(r&7) ->
// fragment ds_read_b128 hits every bank exactly 8 dwords (balanced minimum).
// ---------------------------------------------------------------------------
__global__ __launch_bounds__(256)
void flash_attn(const u16* __restrict__ qkv, const u16* __restrict__ Vt,
                u16* __restrict__ attn) {
    __shared__ __align__(16) u16 Ks[64 * 128];    // 16 KB
    __shared__ __align__(16) u16 Vs[128 * 64];    // 16 KB
    __shared__ __align__(16) u16 Ps[4][32][72];   // 18 KB, wave-private
    const int tid = threadIdx.x, wid = tid >> 6, lane = tid & 63;
    const int q4 = lane >> 4, n16 = lane & 15;
    const int b = blockIdx.y >> 4, h = blockIdx.y & 15;
    const int kvh = h >> 1;
    const long rowbase = (long)b * 2048;
    const long qbase = rowbase + (long)blockIdx.x * 128 + wid * 32;

    const u16* Kbase = qkv + rowbase * 4096 + 2048 + kvh * 128;     // + t*4096 + d
    const u16* Vbase = Vt + ((long)(b * 8 + kvh) * 128) * 2048;     // + d*2048 + t

    // staging maps (per wave, 4 instrs each for K and V)
    // K instr i: row r = wid*16 + i*4 + (lane>>4), slot = lane&15,
    //            global chunk g = slot ^ (r&7); LDS = Ks + (wid*16+i*4)*128 + lane*8
    const int krow_off = lane >> 4;                   // 0..3
    const int kslot = lane & 15;
    // V instr i: row d = wid*32 + i*8 + (lane>>3), slot = lane&7, g = slot^(d&7)
    const int vrow_off = lane >> 3;                   // 0..7
    const int vslot = lane & 7;
    const int vg = vslot ^ vrow_off;                  // d&7 == lane>>3 here

    // Q B-frags (resident; once per block, gather is amortized)
    bf16x8 qf[2][4];
#pragma unroll
    for (int qb = 0; qb < 2; qb++) {
        const u16* p = qkv + (qbase + qb * 16 + n16) * 4096 + h * 128;
#pragma unroll
        for (int c = 0; c < 4; c++) qf[qb][c] = *(const bf16x8*)(p + c * 32 + q4 * 8);
    }

    f32x4 o[2][8];
#pragma unroll
    for (int i = 0; i < 2; i++)
#pragma unroll
        for (int j = 0; j < 8; j++) o[i][j] = (f32x4){0.f, 0.f, 0.f, 0.f};
    float l_i[2] = {0.f, 0.f};
    const float SHIFT = 18.0f;            // > 16.33 hard bound from RMSNorm

    const int swz = n16 & 7;              // fragment-read swizzle key

    for (int kt = 0; kt < 2048; kt += 64) {
        // ---- stage K (4 instrs) and V^T (4 instrs), coalesced ----
#pragma unroll
        for (int i = 0; i < 4; i++) {
            int r = wid * 16 + i * 4 + krow_off;
            int g = kslot ^ (r & 7);
            gl_lds16(Kbase + (long)(kt + r) * 4096 + g * 8,
                     Ks + (wid * 16 + i * 4) * 128 + lane * 8);
        }
#pragma unroll
        for (int i = 0; i < 4; i++) {
            int d = wid * 32 + i * 8 + vrow_off;
            gl_lds16(Vbase + (long)d * 2048 + kt + vg * 8,
                     Vs + (wid * 32 + i * 8) * 64 + lane * 8);
        }
        __syncthreads();   // drains vmcnt, then barrier

        // ---- S^T = K Q^T from LDS ----
        f32x4 s[2][4];
#pragma unroll
        for (int qb = 0; qb < 2; qb++)
#pragma unroll
            for (int kb = 0; kb < 4; kb++) s[qb][kb] = (f32x4){0.f, 0.f, 0.f, 0.f};
#pragma unroll
        for (int c = 0; c < 4; c++) {
            bf16x8 kf[4];
#pragma unroll
            for (int kb = 0; kb < 4; kb++) {
                int slot = (c * 4 + q4) ^ swz;
                kf[kb] = *(const bf16x8*)&Ks[(kb * 16 + n16) * 128 + slot * 8];
            }
#pragma unroll
            for (int qb = 0; qb < 2; qb++)
#pragma unroll
                for (int kb = 0; kb < 4; kb++)
                    s[qb][kb] = mfma_bf16(kf[kb], qf[qb][c], s[qb][kb]);
        }

        // ---- fixed-shift exp2; accumulate l per lane; pack P to bf16 ----
#pragma unroll
        for (int qb = 0; qb < 2; qb++) {
            float sum = 0.f;
#pragma unroll
            for (int kb = 0; kb < 4; kb++) {
                float p0 = exp2f(s[qb][kb][0] - SHIFT);
                float p1 = exp2f(s[qb][kb][1] - SHIFT);
                float p2 = exp2f(s[qb][kb][2] - SHIFT);
                float p3 = exp2f(s[qb][kb][3] - SHIFT);
                sum += (p0 + p1) + (p2 + p3);
                *(uint2*)&Ps[wid][qb * 16 + n16][kb * 16 + q4 * 4] =
                    make_uint2(packtrunc(p0, p1), packtrunc(p2, p3));
            }
            l_i[qb] += sum;
        }

        // ---- PV: A = P-frag (wave-private LDS), B = V^T-frag (swizzled LDS) ----
#pragma unroll
        for (int kc = 0; kc < 2; kc++) {
            bf16x8 vf[8];
#pragma unroll
            for (int nbh = 0; nbh < 8; nbh++) {
                int slot = (kc * 4 + q4) ^ swz;
                vf[nbh] = *(const bf16x8*)&Vs[(nbh * 16 + n16) * 64 + slot * 8];
            }
#pragma unroll
            for (int qb = 0; qb < 2; qb++) {
                bf16x8 pf = *(const bf16x8*)&Ps[wid][qb * 16 + n16][kc * 32 + q4 * 8];
#pragma unroll
                for (int nbh = 0; nbh < 8; nbh++)
                    o[qb][nbh] = mfma_bf16(pf, vf[nbh], o[qb][nbh]);
            }
        }
        __syncthreads();   // all reads done before next stage overwrites
    }

    // ---- reduce l across the 4 quads ----
#pragma unroll
    for (int qb = 0; qb < 2; qb++) {
        l_i[qb] += __shfl_xor(l_i[qb], 16);
        l_i[qb] += __shfl_xor(l_i[qb], 32);
    }

    // ---- epilogue: O /= l, write bf16 attn[8192][2048] ----
#pragma unroll
    for (int qb = 0; qb < 2; qb++) {
        float linv = 1.0f / l_i[qb];
        float l4[4];
#pragma unroll
        for (int r = 0; r < 4; r++)
            l4[r] = __shfl(linv, (lane & 48) | (q4 * 4 + r));
#pragma unroll
        for (int r = 0; r < 4; r++) {
            u16* op = attn + (qbase + qb * 16 + q4 * 4 + r) * 2048 + h * 128 + n16;
#pragma unroll
            for (int nbh = 0; nbh < 8; nbh++)
                op[nbh * 16] = f2bf(o[qb][nbh][r] * l4[r]);
        }
    }
}

// ---------------------------------------------------------------------------
// ws layout (bytes), total 125.8 MB:
//   Bt_qkv / Vt  @ 0          16,777,216   (Vt overwrites Bt_qkv after gemm_qkv)
//   Bt_o         @ 16777216    8,388,608
//   xb / attn    @ 25165824   33,554,432   (attn overwrites xb after gemm_qkv)
//   qkv          @ 58720256   67,108,864
// ---------------------------------------------------------------------------
extern "C" void kernel_launch(void* const* d_in, const int* in_sizes, int n_in,
                              void* d_out, int out_size, void* d_ws, size_t ws_size,
                              hipStream_t stream) {
    const float* x    = (const float*)d_in[0];
    const float* cosT = (const float*)d_in[1];
    const float* sinT = (const float*)d_in[2];
    const float* Wq   = (const float*)d_in[3];
    const float* Wk   = (const float*)d_in[4];
    const float* Wv   = (const float*)d_in[5];
    const float* Wo   = (const float*)d_in[6];
    const float* qg   = (const float*)d_in[7];
    const float* kg   = (const float*)d_in[8];
    float* out = (float*)d_out;

    char* ws = (char*)d_ws;
    u16* Bt_qkv = (u16*)(ws);
    u16* Vt     = (u16*)(ws);              // reuses Bt_qkv after gemm_qkv
    u16* Bt_o   = (u16*)(ws + 16777216);
    u16* xb     = (u16*)(ws + 25165824);
    u16* attn   = (u16*)(ws + 25165824);   // reuses xb after gemm_qkv
    u16* qkv    = (u16*)(ws + 58720256);

    transpose_f2b<<<dim3(64, 64), 256, 0, stream>>>(Wq, Bt_qkv, 2048, 2048);
    transpose_f2b<<<dim3(32, 64), 256, 0, stream>>>(Wk, Bt_qkv + (size_t)2048 * 2048, 2048, 1024);
    transpose_f2b<<<dim3(32, 64), 256, 0, stream>>>(Wv, Bt_qkv + (size_t)3072 * 2048, 2048, 1024);
    transpose_f2b<<<dim3(64, 64), 256, 0, stream>>>(Wo, Bt_o, 2048, 2048);
    cast_f2b<<<dim3(8192), 256, 0, stream>>>(x, xb);

    gemm_bt_bf16<false><<<dim3(32, 64), 256, 0, stream>>>(xb, Bt_qkv, qkv, 8192, 4096, 2048);

    transpose_v<<<dim3(32, 256), 256, 0, stream>>>(qkv, Vt);
    rmsnorm_rope<<<dim3(49152), 256, 0, stream>>>(qkv, cosT, sinT, qg, kg);

    flash_attn<<<dim3(16, 64), 256, 0, stream>>>(qkv, Vt, attn);

    gemm_bt_bf16<true><<<dim3(16, 64), 256, 0, stream>>>(attn, Bt_o, out, 8192, 2048, 2048);
}